// Round 14
// baseline (55.394 us; speedup 1.0000x reference)
//
#include <hip/hip_runtime.h>
#include <hip/hip_bf16.h>

#define STUN   50000
#define BATCH  4096
#define LOG2E  1.4426950408889634f

__device__ __forceinline__ float fexp2(float x){ return __builtin_amdgcn_exp2f(x); }
__device__ __forceinline__ float frcp (float x){ return __builtin_amdgcn_rcpf(x); }
__device__ __forceinline__ float fsig (float x){ return frcp(1.0f + fexp2(-LOG2E * x)); }

// ---------------------------------------------------------------------------
// K0: transposes + E-matrix precompute. 960 blocks x 128 threads. (r12-proven)
//   kleT  [u=64][idx=128]  = kle[idx][u]
//   fc1T/fc2T [u=192][128] = fcW[idx][u]
//   W1aT/W2aT [u=128][128] = W[idx][u]          (the 'a' half, u<128)
//   E1i/E2i [j4=32][k=128][4] = exp2(-log2e * sum_t kle[k][t]*W[j4*4+c][128+t])
// ---------------------------------------------------------------------------
__global__ __launch_bounds__(128) void k_pre(
    const float* __restrict__ kle,
    const float* __restrict__ W1,
    const float* __restrict__ W2,
    const float* __restrict__ fc1_W,
    const float* __restrict__ fc2_W,
    float* __restrict__ kleT,
    float* __restrict__ fc1T,
    float* __restrict__ fc2T,
    float* __restrict__ W1aT,
    float* __restrict__ W2aT,
    float* __restrict__ E1i,
    float* __restrict__ E2i)
{
    const int bid = blockIdx.x;
    const int t   = threadIdx.x;   // 0..127
    if (bid < 64) {
        const int u = bid;
        kleT[u * 128 + t] = kle[t * 64 + u];
    } else if (bid < 256) {
        const int u = bid - 64;
        fc1T[u * 128 + t] = fc1_W[t * 192 + u];
    } else if (bid < 448) {
        const int u = bid - 256;
        fc2T[u * 128 + t] = fc2_W[t * 192 + u];
    } else if (bid < 576) {
        const int u = bid - 448;
        W1aT[u * 128 + t] = W1[t * 192 + u];
    } else if (bid < 704) {
        const int u = bid - 576;
        W2aT[u * 128 + t] = W2[t * 192 + u];
    } else if (bid < 832) {
        const int j = bid - 704;          // lane t = k
        float acc = 0.f;
        #pragma unroll
        for (int u4 = 0; u4 < 16; ++u4) {
            const float4 kv = *(const float4*)&kle[t * 64 + u4 * 4];
            const float4 wv = *(const float4*)&W1[j * 192 + 128 + u4 * 4];
            acc += kv.x * wv.x + kv.y * wv.y + kv.z * wv.z + kv.w * wv.w;
        }
        E1i[((j >> 2) * 128 + t) * 4 + (j & 3)] = fexp2(-LOG2E * acc);
    } else {
        const int j = bid - 832;
        float acc = 0.f;
        #pragma unroll
        for (int u4 = 0; u4 < 16; ++u4) {
            const float4 kv = *(const float4*)&kle[t * 64 + u4 * 4];
            const float4 wv = *(const float4*)&W2[j * 192 + 128 + u4 * 4];
            acc += kv.x * wv.x + kv.y * wv.y + kv.z * wv.z + kv.w * wv.w;
        }
        E2i[((j >> 2) * 128 + t) * 4 + (j & 3)] = fexp2(-LOG2E * acc);
    }
}

// ---------------------------------------------------------------------------
// K_FUSED v7: 4 b/block, 512 threads, grid 1024 -> 4 blocks/CU = 32 waves/CU
// (8 waves/SIMD — chip cap). LDS ~17 KB. No ps buffer: prep partials are
// combined INTRA-WAVE via shfl_xor (lanes split u 4-ways).
// Prep mapping: wave w -> (half = w&1, iqo = w>>1); lane l: ul = l>>4
// (u-quarter), bh2 = (l>>3)&1 (b-pair), iql = l&7 -> iq = iqo*8+iql.
// Thread: acc[4 idx][2 b]. Combine: shfl_xor 16, 32; ul==0 lanes write.
// Main: k = t&127 on lanes, bh = t>>7 -> 1 b x 128 j per thread.
// ---------------------------------------------------------------------------
__global__ __launch_bounds__(512, 4) void k_fused(
    const int*   __restrict__ stu_id,
    const int*   __restrict__ exer_id,
    const float* __restrict__ student_emb,   // (2*50000, 64) flat
    const float* __restrict__ prompt_stu,    // (50000, 64)
    const float* __restrict__ k_diff,        // (20000, 64)
    const float* __restrict__ s_exer,        // (2, 64)
    const float* __restrict__ kleT,          // (64,128)
    const float* __restrict__ fc1T,          // (192,128)
    const float* __restrict__ fc2T,
    const float* __restrict__ W1aT,          // (128,128)
    const float* __restrict__ W2aT,
    const float* __restrict__ fc1_b,
    const float* __restrict__ fc2_b,
    const float* __restrict__ E1i,           // [j4=32][k=128][4]
    const float* __restrict__ E2i,
    const float* __restrict__ W3,
    const float* __restrict__ b3,
    const float* __restrict__ kn,
    float* __restrict__ out)
{
    __shared__ __align__(16) float sh_in [4][64][4];    // 4 KB [src][u][b]
    __shared__ __align__(16) float sh_old[2][128][4];   // 4 KB [half][idx][b]
    __shared__ __align__(16) float sh_e  [2][128][4];   // 4 KB
    __shared__ __align__(16) float ses   [2][4][128];   // 4 KB [mat][b][j]
    __shared__ float red_o[8];
    __shared__ float red_k[8];

    const int t  = threadIdx.x;           // 0..511
    const int b0 = blockIdx.x * 4;

    // ---- gather: 128 threads per local b; sp splits sources ----
    {
        const int g   = t >> 7;
        const int sp  = (t >> 6) & 1;
        const int u   = t & 63;
        const int sid = stu_id[b0 + g];
        const int eid = exer_id[b0 + g];
        if (sp == 0) {
            sh_in[0][u][g] = student_emb[sid * 64 + u];
            sh_in[1][u][g] = fsig(k_diff[eid * 64 + u]);
        } else {
            const int er = (eid >= 10000) ? 1 : 0;
            sh_in[2][u][g] = prompt_stu[(sid % STUN) * 64 + u];
            sh_in[3][u][g] = fsig(s_exer[er * 64 + u]);
        }
    }
    __syncthreads();

    const int w    = t >> 6;              // wave 0..7
    const int half = w & 1;
    const int iqo  = w >> 1;              // 0..3
    const int l    = t & 63;
    const int ul   = l >> 4;              // u-quarter 0..3
    const int bh2  = (l >> 3) & 1;        // b-pair
    const int iql  = l & 7;
    const int iq   = iqo * 8 + iql;       // 0..31 -> idx = iq*4+c

    float a[4][2];

#define CLR { _Pragma("unroll") for (int c = 0; c < 4; ++c) { a[c][0] = 0.f; a[c][1] = 0.f; } }

#define GSTEP2(wp, xp) { \
    const float4 w4 = *(const float4*)(wp); \
    const float2 x2 = *(const float2*)(xp); \
    a[0][0] = fmaf(w4.x, x2.x, a[0][0]); a[0][1] = fmaf(w4.x, x2.y, a[0][1]); \
    a[1][0] = fmaf(w4.y, x2.x, a[1][0]); a[1][1] = fmaf(w4.y, x2.y, a[1][1]); \
    a[2][0] = fmaf(w4.z, x2.x, a[2][0]); a[2][1] = fmaf(w4.z, x2.y, a[2][1]); \
    a[3][0] = fmaf(w4.w, x2.x, a[3][0]); a[3][1] = fmaf(w4.w, x2.y, a[3][1]); }

#define COMBINE { _Pragma("unroll") for (int c = 0; c < 4; ++c) { \
    _Pragma("unroll") for (int b = 0; b < 2; ++b) { \
        float v = a[c][b]; \
        v += __shfl_xor(v, 16); \
        v += __shfl_xor(v, 32); \
        a[c][b] = v; } } }

    // ---- stage 1: old[idx] = sig( dot64(x_row, kle[idx]) ) ----
    CLR;
    {
        const int u0 = ul * 16;
        #pragma unroll
        for (int u = u0; u < u0 + 16; ++u)
            GSTEP2(&kleT[u * 128 + iq * 4], &sh_in[half][u][bh2 * 2]);
    }
    COMBINE;
    if (ul == 0) {
        #pragma unroll
        for (int c = 0; c < 4; ++c) {
            const float2 v2 = make_float2(fsig(a[c][0]), fsig(a[c][1]));
            *(float2*)&sh_old[half][iq * 4 + c][bh2 * 2] = v2;
        }
    }
    __syncthreads();

    // ---- stage 2: e[idx] = sig( [p, old] @ fcW[idx] + fcb[idx] ) ----
    CLR;
    {
        const float* fcT = half ? fc2T : fc1T;
        const int up = ul * 16;
        #pragma unroll
        for (int u = up; u < up + 16; ++u)
            GSTEP2(&fcT[u * 128 + iq * 4], &sh_in[2 + half][u][bh2 * 2]);
        const int uo = ul * 32;
        #pragma unroll
        for (int u = uo; u < uo + 32; ++u)
            GSTEP2(&fcT[(64 + u) * 128 + iq * 4], &sh_old[half][u][bh2 * 2]);
    }
    COMBINE;
    if (ul == 0) {
        const float* fcb = half ? fc2_b : fc1_b;
        #pragma unroll
        for (int c = 0; c < 4; ++c) {
            const float bias = fcb[iq * 4 + c];
            const float2 v2 = make_float2(fsig(a[c][0] + bias), fsig(a[c][1] + bias));
            *(float2*)&sh_e[half][iq * 4 + c][bh2 * 2] = v2;
        }
    }
    __syncthreads();

    // ---- stage 3: ses[mat][b][j] = exp2( -log2e * dot128(e, Wa[j]) ) ----
    CLR;
    {
        const float* WT = half ? W2aT : W1aT;
        const int u0 = ul * 32;
        #pragma unroll
        for (int u = u0; u < u0 + 32; ++u)
            GSTEP2(&WT[u * 128 + iq * 4], &sh_e[half][u][bh2 * 2]);
    }
    COMBINE;
    if (ul == 0) {
        #pragma unroll
        for (int c = 0; c < 4; ++c) {
            ses[half][bh2 * 2 + 0][iq * 4 + c] = fexp2(-LOG2E * a[c][0]);
            ses[half][bh2 * 2 + 1][iq * 4 + c] = fexp2(-LOG2E * a[c][1]);
        }
    }
#undef CLR
#undef GSTEP2
#undef COMBINE
    __syncthreads();

    // ---- main loop: k = t&127 on lanes, bh = t>>7 -> 1 b x 128 j ----
    const int k  = t & 127;
    const int bh = t >> 7;

    const float4* E1v = (const float4*)E1i + k;
    const float4* E2v = (const float4*)E2i + k;
    const float* s1 = &ses[0][bh][0];
    const float* s2 = &ses[1][bh][0];

    float acc = 0.f;

#define COMP(s1c, s2c, e1c, e2c, w3c) { \
        const float uu = (s1c) * (e1c); \
        const float vv = (s2c) * (e2c); \
        const float dd = frcp((1.f + uu) * (1.f + vv)); \
        acc = fmaf((vv - uu) * dd, (w3c), acc); }

    #pragma unroll 4
    for (int j4 = 0; j4 < 32; ++j4) {
        const int j = j4 * 4;
        const float4 e1 = E1v[j4 * 128];
        const float4 e2 = E2v[j4 * 128];
        const float4 w3 = *(const float4*)&W3[j];
        const float4 p1 = *(const float4*)&s1[j];
        const float4 p2 = *(const float4*)&s2[j];
        COMP(p1.x, p2.x, e1.x, e2.x, w3.x);
        COMP(p1.y, p2.y, e1.y, e2.y, w3.y);
        COMP(p1.z, p2.z, e1.z, e2.z, w3.z);
        COMP(p1.w, p2.w, e1.w, e2.w, w3.w);
    }
#undef COMP

    // ---- epilogue: outer sigmoid + kn-weighted mean over k ----
    const float bb3 = b3[0];
    const float o   = fsig(acc + bb3);
    const float knv = kn[(b0 + bh) * 128 + k];
    float co = o * knv, ck = knv;
    #pragma unroll
    for (int off = 1; off < 64; off <<= 1) {
        co += __shfl_xor(co, off);
        ck += __shfl_xor(ck, off);
    }
    if ((t & 63) == 0) {
        red_o[w] = co;
        red_k[w] = ck;
    }
    __syncthreads();
    if (t < 4) {
        const float so = red_o[2 * t] + red_o[2 * t + 1];
        const float sk = red_k[2 * t] + red_k[2 * t + 1];
        out[b0 + t] = so / sk;
    }
}

// ---------------------------------------------------------------------------
extern "C" void kernel_launch(void* const* d_in, const int* in_sizes, int n_in,
                              void* d_out, int out_size, void* d_ws, size_t ws_size,
                              hipStream_t stream)
{
    const int*   stu_id      = (const int*)  d_in[0];
    const int*   exer_id     = (const int*)  d_in[1];
    const float* kn_emb      = (const float*)d_in[2];
    const float* student_emb = (const float*)d_in[3];
    const float* prompt_stu  = (const float*)d_in[4];
    const float* kle         = (const float*)d_in[5];
    const float* k_diff      = (const float*)d_in[6];
    const float* s_exer      = (const float*)d_in[7];
    const float* W1          = (const float*)d_in[8];
    const float* W2          = (const float*)d_in[9];
    const float* W3          = (const float*)d_in[10];
    const float* b3          = (const float*)d_in[11];
    const float* fc1_W       = (const float*)d_in[12];
    const float* fc1_b       = (const float*)d_in[13];
    const float* fc2_W       = (const float*)d_in[14];
    const float* fc2_b       = (const float*)d_in[15];
    float* out = (float*)d_out;

    float* ws   = (float*)d_ws;
    float* kleT = ws;                        // 64*128   = 8192
    float* fc1T = kleT + 8192;               // 192*128  = 24576
    float* fc2T = fc1T + 24576;
    float* W1aT = fc2T + 24576;              // 128*128  = 16384
    float* W2aT = W1aT + 16384;
    float* E1i  = W2aT + 16384;              // 128*128  = 16384
    float* E2i  = E1i  + 16384;

    k_pre  <<<960, 128, 0, stream>>>(kle, W1, W2, fc1_W, fc2_W,
                                     kleT, fc1T, fc2T, W1aT, W2aT, E1i, E2i);
    k_fused<<<BATCH / 4, 512, 0, stream>>>(stu_id, exer_id, student_emb, prompt_stu,
                                           k_diff, s_exer, kleT, fc1T, fc2T,
                                           W1aT, W2aT, fc1_b, fc2_b,
                                           E1i, E2i, W3, b3, kn_emb, out);
}

// Round 15
// 49.142 us; speedup vs baseline: 1.1272x; 1.1272x over previous
//
#include <hip/hip_runtime.h>
#include <hip/hip_bf16.h>

#define STUN   50000
#define BATCH  4096
#define LOG2E  1.4426950408889634f

__device__ __forceinline__ float fexp2(float x){ return __builtin_amdgcn_exp2f(x); }
__device__ __forceinline__ float frcp (float x){ return __builtin_amdgcn_rcpf(x); }
__device__ __forceinline__ float fsig (float x){ return frcp(1.0f + fexp2(-LOG2E * x)); }

// ---------------------------------------------------------------------------
// K0: transposes + E-matrix precompute. 960 blocks x 128 threads. (r12-proven)
//   kleT  [u=64][idx=128]  = kle[idx][u]
//   fc1T/fc2T [u=192][128] = fcW[idx][u]
//   W1aT/W2aT [u=128][128] = W[idx][u]          (the 'a' half, u<128)
//   E1i/E2i [j4=32][k=128][4] = exp2(-log2e * sum_t kle[k][t]*W[j4*4+c][128+t])
// ---------------------------------------------------------------------------
__global__ __launch_bounds__(128) void k_pre(
    const float* __restrict__ kle,
    const float* __restrict__ W1,
    const float* __restrict__ W2,
    const float* __restrict__ fc1_W,
    const float* __restrict__ fc2_W,
    float* __restrict__ kleT,
    float* __restrict__ fc1T,
    float* __restrict__ fc2T,
    float* __restrict__ W1aT,
    float* __restrict__ W2aT,
    float* __restrict__ E1i,
    float* __restrict__ E2i)
{
    const int bid = blockIdx.x;
    const int t   = threadIdx.x;   // 0..127
    if (bid < 64) {
        const int u = bid;
        kleT[u * 128 + t] = kle[t * 64 + u];
    } else if (bid < 256) {
        const int u = bid - 64;
        fc1T[u * 128 + t] = fc1_W[t * 192 + u];
    } else if (bid < 448) {
        const int u = bid - 256;
        fc2T[u * 128 + t] = fc2_W[t * 192 + u];
    } else if (bid < 576) {
        const int u = bid - 448;
        W1aT[u * 128 + t] = W1[t * 192 + u];
    } else if (bid < 704) {
        const int u = bid - 576;
        W2aT[u * 128 + t] = W2[t * 192 + u];
    } else if (bid < 832) {
        const int j = bid - 704;          // lane t = k
        float acc = 0.f;
        #pragma unroll
        for (int u4 = 0; u4 < 16; ++u4) {
            const float4 kv = *(const float4*)&kle[t * 64 + u4 * 4];
            const float4 wv = *(const float4*)&W1[j * 192 + 128 + u4 * 4];
            acc += kv.x * wv.x + kv.y * wv.y + kv.z * wv.z + kv.w * wv.w;
        }
        E1i[((j >> 2) * 128 + t) * 4 + (j & 3)] = fexp2(-LOG2E * acc);
    } else {
        const int j = bid - 832;
        float acc = 0.f;
        #pragma unroll
        for (int u4 = 0; u4 < 16; ++u4) {
            const float4 kv = *(const float4*)&kle[t * 64 + u4 * 4];
            const float4 wv = *(const float4*)&W2[j * 192 + 128 + u4 * 4];
            acc += kv.x * wv.x + kv.y * wv.y + kv.z * wv.z + kv.w * wv.w;
        }
        E2i[((j >> 2) * 128 + t) * 4 + (j & 3)] = fexp2(-LOG2E * acc);
    }
}

// ---------------------------------------------------------------------------
// K_FUSED v8: 8 b/block, 512 threads, grid 512 (2 blocks/CU, 16 waves/CU).
// Weight L2 traffic halved vs r13 (246 MB). No ps buffer: u-split lives in
// lane bits (ul = l>>4); partials combined with shfl_xor 16,32.
// Prep map: wave w -> (half = w&1, iqo = w>>1); lane: ul = l>>4, bs=(l>>3)&1,
//   iql = l&7 -> iq = iqo*8+iql (0..31), b-quad = bs*4. Thread: a[4 c][4 b].
//   u interleaved mod 4 (u = ul, ul+4, ...) -> 4 consecutive rows per wave
//   read together -> x-broadcast spans all 32 banks (no conflict).
// Main (r13-proven form): k = t&127, bh = t>>7 -> 2 b x 128 j per thread.
//   u = es1*E1, v = es2*E2, acc += (v-u)*rcp((1+u)(1+v))*w3.
// LDS ~33 KB.
// ---------------------------------------------------------------------------
__global__ __launch_bounds__(512, 4) void k_fused(
    const int*   __restrict__ stu_id,
    const int*   __restrict__ exer_id,
    const float* __restrict__ student_emb,   // (2*50000, 64) flat
    const float* __restrict__ prompt_stu,    // (50000, 64)
    const float* __restrict__ k_diff,        // (20000, 64)
    const float* __restrict__ s_exer,        // (2, 64)
    const float* __restrict__ kleT,          // (64,128)
    const float* __restrict__ fc1T,          // (192,128)
    const float* __restrict__ fc2T,
    const float* __restrict__ W1aT,          // (128,128)
    const float* __restrict__ W2aT,
    const float* __restrict__ fc1_b,
    const float* __restrict__ fc2_b,
    const float* __restrict__ E1i,           // [j4=32][k=128][4]
    const float* __restrict__ E2i,
    const float* __restrict__ W3,
    const float* __restrict__ b3,
    const float* __restrict__ kn,
    float* __restrict__ out)
{
    __shared__ __align__(16) float sh_in [4][64][8];    //  8 KB [src][u][b]
    __shared__ __align__(16) float sh_old[2][128][8];   //  8 KB [half][idx][b]
    __shared__ __align__(16) float sh_e  [2][128][8];   //  8 KB
    __shared__ __align__(16) float ses   [2][8][128];   //  8 KB [mat][b][j]
    __shared__ float red_o[8][2];
    __shared__ float red_k[8][2];

    const int t  = threadIdx.x;           // 0..511
    const int b0 = blockIdx.x * 8;

    // ---- gather: 64 threads per local batch elem, coalesced ----
    {
        const int g   = t >> 6;
        const int u   = t & 63;
        const int sid = stu_id[b0 + g];
        const int eid = exer_id[b0 + g];
        const int er  = (eid >= 10000) ? 1 : 0;
        sh_in[0][u][g] = student_emb[sid * 64 + u];
        sh_in[1][u][g] = fsig(k_diff[eid * 64 + u]);
        sh_in[2][u][g] = prompt_stu[(sid % STUN) * 64 + u];
        sh_in[3][u][g] = fsig(s_exer[er * 64 + u]);
    }
    __syncthreads();

    const int w    = t >> 6;              // wave 0..7
    const int half = w & 1;
    const int iqo  = w >> 1;              // 0..3
    const int l    = t & 63;
    const int ul   = l >> 4;              // u-split 0..3 (lane bits 4-5)
    const int bs   = (l >> 3) & 1;        // b-quad select
    const int iql  = l & 7;
    const int iq   = iqo * 8 + iql;       // 0..31 -> idx = iq*4+c
    const int bq   = bs * 4;

    float a[4][4];

#define CLR { _Pragma("unroll") for (int c = 0; c < 4; ++c) \
              _Pragma("unroll") for (int b = 0; b < 4; ++b) a[c][b] = 0.f; }

#define FMAC(c, wc) { \
    a[c][0] = fmaf(wc, x0.x, a[c][0]); a[c][1] = fmaf(wc, x0.y, a[c][1]); \
    a[c][2] = fmaf(wc, x0.z, a[c][2]); a[c][3] = fmaf(wc, x0.w, a[c][3]); }

#define GSTEP(wp, xp) { \
    const float4 w4 = *(const float4*)(wp); \
    const float4 x0 = *(const float4*)(xp); \
    FMAC(0, w4.x); FMAC(1, w4.y); FMAC(2, w4.z); FMAC(3, w4.w); }

#define COMBINE { _Pragma("unroll") for (int c = 0; c < 4; ++c) \
    _Pragma("unroll") for (int b = 0; b < 4; ++b) { \
        float v = a[c][b]; \
        v += __shfl_xor(v, 16); \
        v += __shfl_xor(v, 32); \
        a[c][b] = v; } }

    // ---- stage 1: old[idx] = sig( dot64(x_row, kle[idx]) ) ----
    CLR;
    #pragma unroll 4
    for (int u = ul; u < 64; u += 4)
        GSTEP(&kleT[u * 128 + iq * 4], &sh_in[half][u][bq]);
    COMBINE;
    if (ul == 0) {
        #pragma unroll
        for (int c = 0; c < 4; ++c)
            *(float4*)&sh_old[half][iq * 4 + c][bq] =
                make_float4(fsig(a[c][0]), fsig(a[c][1]), fsig(a[c][2]), fsig(a[c][3]));
    }
    __syncthreads();

    // ---- stage 2: e[idx] = sig( [p, old] @ fcW[idx] + fcb[idx] ) ----
    CLR;
    {
        const float* fcT = half ? fc2T : fc1T;
        #pragma unroll 4
        for (int u = ul; u < 64; u += 4)
            GSTEP(&fcT[u * 128 + iq * 4], &sh_in[2 + half][u][bq]);
        #pragma unroll 4
        for (int u = 64 + ul; u < 192; u += 4)
            GSTEP(&fcT[u * 128 + iq * 4], &sh_old[half][u - 64][bq]);
    }
    COMBINE;
    if (ul == 0) {
        const float* fcb = half ? fc2_b : fc1_b;
        #pragma unroll
        for (int c = 0; c < 4; ++c) {
            const float bias = fcb[iq * 4 + c];
            *(float4*)&sh_e[half][iq * 4 + c][bq] =
                make_float4(fsig(a[c][0] + bias), fsig(a[c][1] + bias),
                            fsig(a[c][2] + bias), fsig(a[c][3] + bias));
        }
    }
    __syncthreads();

    // ---- stage 3: ses[mat][b][j] = exp2( -log2e * dot128(e, Wa[j]) ) ----
    CLR;
    {
        const float* WT = half ? W2aT : W1aT;
        #pragma unroll 4
        for (int u = ul; u < 128; u += 4)
            GSTEP(&WT[u * 128 + iq * 4], &sh_e[half][u][bq]);
    }
    COMBINE;
    if (ul == 0) {
        #pragma unroll
        for (int c = 0; c < 4; ++c) {
            #pragma unroll
            for (int b = 0; b < 4; ++b)
                ses[half][bq + b][iq * 4 + c] = fexp2(-LOG2E * a[c][b]);
        }
    }
#undef CLR
#undef FMAC
#undef GSTEP
#undef COMBINE
    __syncthreads();

    // ---- main loop: k = t&127 on lanes, bh = t>>7 -> 2 b x 128 j ----
    const int k  = t & 127;
    const int bh = t >> 7;                // 0..3 -> b-pair
    const int i0 = bh * 2;

    const float4* E1v = (const float4*)E1i + k;
    const float4* E2v = (const float4*)E2i + k;
    const float* s1a = &ses[0][i0 + 0][0];
    const float* s2a = &ses[1][i0 + 0][0];
    const float* s1b = &ses[0][i0 + 1][0];
    const float* s2b = &ses[1][i0 + 1][0];

    float acc0 = 0.f, acc1 = 0.f;

#define COMP(acc, s1c, s2c, e1c, e2c, w3c) { \
        const float uu = (s1c) * (e1c); \
        const float vv = (s2c) * (e2c); \
        const float dd = frcp((1.f + uu) * (1.f + vv)); \
        acc = fmaf((vv - uu) * dd, (w3c), acc); }

    #pragma unroll 4
    for (int j4 = 0; j4 < 32; ++j4) {
        const int j = j4 * 4;
        const float4 e1 = E1v[j4 * 128];
        const float4 e2 = E2v[j4 * 128];
        const float4 w3 = *(const float4*)&W3[j];
        const float4 p1a = *(const float4*)&s1a[j];
        const float4 p2a = *(const float4*)&s2a[j];
        const float4 p1b = *(const float4*)&s1b[j];
        const float4 p2b = *(const float4*)&s2b[j];
        COMP(acc0, p1a.x, p2a.x, e1.x, e2.x, w3.x);
        COMP(acc0, p1a.y, p2a.y, e1.y, e2.y, w3.y);
        COMP(acc0, p1a.z, p2a.z, e1.z, e2.z, w3.z);
        COMP(acc0, p1a.w, p2a.w, e1.w, e2.w, w3.w);
        COMP(acc1, p1b.x, p2b.x, e1.x, e2.x, w3.x);
        COMP(acc1, p1b.y, p2b.y, e1.y, e2.y, w3.y);
        COMP(acc1, p1b.z, p2b.z, e1.z, e2.z, w3.z);
        COMP(acc1, p1b.w, p2b.w, e1.w, e2.w, w3.w);
    }
#undef COMP

    // ---- epilogue: outer sigmoid + kn-weighted mean over k ----
    const float bb3 = b3[0];
    const float o0  = fsig(acc0 + bb3);
    const float o1  = fsig(acc1 + bb3);
    const float kn0 = kn[(b0 + i0 + 0) * 128 + k];
    const float kn1 = kn[(b0 + i0 + 1) * 128 + k];
    float co0 = o0 * kn0, ck0 = kn0;
    float co1 = o1 * kn1, ck1 = kn1;
    #pragma unroll
    for (int off = 1; off < 64; off <<= 1) {
        co0 += __shfl_xor(co0, off);
        ck0 += __shfl_xor(ck0, off);
        co1 += __shfl_xor(co1, off);
        ck1 += __shfl_xor(ck1, off);
    }
    if ((t & 63) == 0) {
        red_o[w][0] = co0; red_o[w][1] = co1;
        red_k[w][0] = ck0; red_k[w][1] = ck1;
    }
    __syncthreads();
    if (t < 8) {
        const int p = t >> 1;             // b-pair
        const int i = t & 1;
        const float so = red_o[p * 2][i] + red_o[p * 2 + 1][i];
        const float sk = red_k[p * 2][i] + red_k[p * 2 + 1][i];
        out[b0 + t] = so / sk;
    }
}

// ---------------------------------------------------------------------------
extern "C" void kernel_launch(void* const* d_in, const int* in_sizes, int n_in,
                              void* d_out, int out_size, void* d_ws, size_t ws_size,
                              hipStream_t stream)
{
    const int*   stu_id      = (const int*)  d_in[0];
    const int*   exer_id     = (const int*)  d_in[1];
    const float* kn_emb      = (const float*)d_in[2];
    const float* student_emb = (const float*)d_in[3];
    const float* prompt_stu  = (const float*)d_in[4];
    const float* kle         = (const float*)d_in[5];
    const float* k_diff      = (const float*)d_in[6];
    const float* s_exer      = (const float*)d_in[7];
    const float* W1          = (const float*)d_in[8];
    const float* W2          = (const float*)d_in[9];
    const float* W3          = (const float*)d_in[10];
    const float* b3          = (const float*)d_in[11];
    const float* fc1_W       = (const float*)d_in[12];
    const float* fc1_b       = (const float*)d_in[13];
    const float* fc2_W       = (const float*)d_in[14];
    const float* fc2_b       = (const float*)d_in[15];
    float* out = (float*)d_out;

    float* ws   = (float*)d_ws;
    float* kleT = ws;                        // 64*128   = 8192
    float* fc1T = kleT + 8192;               // 192*128  = 24576
    float* fc2T = fc1T + 24576;
    float* W1aT = fc2T + 24576;              // 128*128  = 16384
    float* W2aT = W1aT + 16384;
    float* E1i  = W2aT + 16384;              // 128*128  = 16384
    float* E2i  = E1i  + 16384;

    k_pre  <<<960, 128, 0, stream>>>(kle, W1, W2, fc1_W, fc2_W,
                                     kleT, fc1T, fc2T, W1aT, W2aT, E1i, E2i);
    k_fused<<<BATCH / 8, 512, 0, stream>>>(stu_id, exer_id, student_emb, prompt_stu,
                                           k_diff, s_exer, kleT, fc1T, fc2T,
                                           W1aT, W2aT, fc1_b, fc2_b,
                                           E1i, E2i, W3, b3, kn_emb, out);
}

// Round 16
// 47.420 us; speedup vs baseline: 1.1682x; 1.0363x over previous
//
#include <hip/hip_runtime.h>
#include <hip/hip_bf16.h>

#define STUN   50000
#define BATCH  4096
#define LOG2E  1.4426950408889634f

__device__ __forceinline__ float fexp2(float x){ return __builtin_amdgcn_exp2f(x); }
__device__ __forceinline__ float frcp (float x){ return __builtin_amdgcn_rcpf(x); }
__device__ __forceinline__ float fsig (float x){ return frcp(1.0f + fexp2(-LOG2E * x)); }

// ---------------------------------------------------------------------------
// K0: transposes + E-matrix precompute. 960 blocks x 128 threads. (r12-proven)
// ---------------------------------------------------------------------------
__global__ __launch_bounds__(128) void k_pre(
    const float* __restrict__ kle,
    const float* __restrict__ W1,
    const float* __restrict__ W2,
    const float* __restrict__ fc1_W,
    const float* __restrict__ fc2_W,
    float* __restrict__ kleT,
    float* __restrict__ fc1T,
    float* __restrict__ fc2T,
    float* __restrict__ W1aT,
    float* __restrict__ W2aT,
    float* __restrict__ E1i,
    float* __restrict__ E2i)
{
    const int bid = blockIdx.x;
    const int t   = threadIdx.x;   // 0..127
    if (bid < 64) {
        const int u = bid;
        kleT[u * 128 + t] = kle[t * 64 + u];
    } else if (bid < 256) {
        const int u = bid - 64;
        fc1T[u * 128 + t] = fc1_W[t * 192 + u];
    } else if (bid < 448) {
        const int u = bid - 256;
        fc2T[u * 128 + t] = fc2_W[t * 192 + u];
    } else if (bid < 576) {
        const int u = bid - 448;
        W1aT[u * 128 + t] = W1[t * 192 + u];
    } else if (bid < 704) {
        const int u = bid - 576;
        W2aT[u * 128 + t] = W2[t * 192 + u];
    } else if (bid < 832) {
        const int j = bid - 704;          // lane t = k
        float acc = 0.f;
        #pragma unroll
        for (int u4 = 0; u4 < 16; ++u4) {
            const float4 kv = *(const float4*)&kle[t * 64 + u4 * 4];
            const float4 wv = *(const float4*)&W1[j * 192 + 128 + u4 * 4];
            acc += kv.x * wv.x + kv.y * wv.y + kv.z * wv.z + kv.w * wv.w;
        }
        E1i[((j >> 2) * 128 + t) * 4 + (j & 3)] = fexp2(-LOG2E * acc);
    } else {
        const int j = bid - 832;
        float acc = 0.f;
        #pragma unroll
        for (int u4 = 0; u4 < 16; ++u4) {
            const float4 kv = *(const float4*)&kle[t * 64 + u4 * 4];
            const float4 wv = *(const float4*)&W2[j * 192 + 128 + u4 * 4];
            acc += kv.x * wv.x + kv.y * wv.y + kv.z * wv.z + kv.w * wv.w;
        }
        E2i[((j >> 2) * 128 + t) * 4 + (j & 3)] = fexp2(-LOG2E * acc);
    }
}

// ---------------------------------------------------------------------------
// K_FUSED v9: 8 b/block, 512 threads, grid 512 (2 blocks/CU).
// Prep = r15's weights-read-once shfl-combine, with STRIDE-12 sh_old/sh_e
// (fixes r15's 8-way store conflict: stores now <=4-way, reads ~2-way).
// Main = j-quarter split (jq = t>>7): each (j,k) of E read by exactly ONE
// thread (E/block 512->128 KB); 8 b-accumulators per thread (ILP 8);
// partials combined via red[4][8][128] (conflict-free, lanes on k).
// L2 traffic/chip ~260 MB (vs r13's ~763 MB). LDS ~58 KB.
// ---------------------------------------------------------------------------
__global__ __launch_bounds__(512, 4) void k_fused(
    const int*   __restrict__ stu_id,
    const int*   __restrict__ exer_id,
    const float* __restrict__ student_emb,   // (2*50000, 64) flat
    const float* __restrict__ prompt_stu,    // (50000, 64)
    const float* __restrict__ k_diff,        // (20000, 64)
    const float* __restrict__ s_exer,        // (2, 64)
    const float* __restrict__ kleT,          // (64,128)
    const float* __restrict__ fc1T,          // (192,128)
    const float* __restrict__ fc2T,
    const float* __restrict__ W1aT,          // (128,128)
    const float* __restrict__ W2aT,
    const float* __restrict__ fc1_b,
    const float* __restrict__ fc2_b,
    const float* __restrict__ E1i,           // [j4=32][k=128][4]
    const float* __restrict__ E2i,
    const float* __restrict__ W3,
    const float* __restrict__ b3,
    const float* __restrict__ kn,
    float* __restrict__ out)
{
    __shared__ __align__(16) float sh_in [4][64][8];    //  8 KB [src][u][b]
    __shared__ __align__(16) float sh_old[2][128][12];  // 12 KB (stride-12 pad)
    __shared__ __align__(16) float sh_e  [2][128][12];  // 12 KB
    __shared__ __align__(16) float ses   [2][8][128];   //  8 KB [mat][b][j]
    __shared__ __align__(16) float red   [4][8][128];   // 16 KB [jq][b][k]
    __shared__ float red2_o[8][2];
    __shared__ float red2_k[8][2];

    const int t  = threadIdx.x;           // 0..511
    const int b0 = blockIdx.x * 8;

    // ---- gather: 64 threads per local batch elem, coalesced ----
    {
        const int g   = t >> 6;
        const int u   = t & 63;
        const int sid = stu_id[b0 + g];
        const int eid = exer_id[b0 + g];
        const int er  = (eid >= 10000) ? 1 : 0;
        sh_in[0][u][g] = student_emb[sid * 64 + u];
        sh_in[1][u][g] = fsig(k_diff[eid * 64 + u]);
        sh_in[2][u][g] = prompt_stu[(sid % STUN) * 64 + u];
        sh_in[3][u][g] = fsig(s_exer[er * 64 + u]);
    }
    __syncthreads();

    const int w    = t >> 6;              // wave 0..7
    const int half = w & 1;
    const int iqo  = w >> 1;              // 0..3
    const int l    = t & 63;
    const int ul   = l >> 4;              // u-split 0..3 (lane bits 4-5)
    const int bs   = (l >> 3) & 1;        // b-quad select
    const int iql  = l & 7;
    const int iq   = iqo * 8 + iql;       // 0..31 -> idx = iq*4+c
    const int bq   = bs * 4;

    float a[4][4];

#define CLR { _Pragma("unroll") for (int c = 0; c < 4; ++c) \
              _Pragma("unroll") for (int b = 0; b < 4; ++b) a[c][b] = 0.f; }

#define FMAC(c, wc) { \
    a[c][0] = fmaf(wc, x0.x, a[c][0]); a[c][1] = fmaf(wc, x0.y, a[c][1]); \
    a[c][2] = fmaf(wc, x0.z, a[c][2]); a[c][3] = fmaf(wc, x0.w, a[c][3]); }

#define GSTEP(wp, xp) { \
    const float4 w4 = *(const float4*)(wp); \
    const float4 x0 = *(const float4*)(xp); \
    FMAC(0, w4.x); FMAC(1, w4.y); FMAC(2, w4.z); FMAC(3, w4.w); }

#define COMBINE { _Pragma("unroll") for (int c = 0; c < 4; ++c) \
    _Pragma("unroll") for (int b = 0; b < 4; ++b) { \
        float v = a[c][b]; \
        v += __shfl_xor(v, 16); \
        v += __shfl_xor(v, 32); \
        a[c][b] = v; } }

    // ---- stage 1: old[idx] = sig( dot64(x_row, kle[idx]) ) ----
    CLR;
    #pragma unroll 4
    for (int u = ul; u < 64; u += 4)
        GSTEP(&kleT[u * 128 + iq * 4], &sh_in[half][u][bq]);
    COMBINE;
    if (ul == 0) {
        #pragma unroll
        for (int c = 0; c < 4; ++c)
            *(float4*)&sh_old[half][iq * 4 + c][bq] =
                make_float4(fsig(a[c][0]), fsig(a[c][1]), fsig(a[c][2]), fsig(a[c][3]));
    }
    __syncthreads();

    // ---- stage 2: e[idx] = sig( [p, old] @ fcW[idx] + fcb[idx] ) ----
    CLR;
    {
        const float* fcT = half ? fc2T : fc1T;
        #pragma unroll 4
        for (int u = ul; u < 64; u += 4)
            GSTEP(&fcT[u * 128 + iq * 4], &sh_in[2 + half][u][bq]);
        #pragma unroll 4
        for (int u = 64 + ul; u < 192; u += 4)
            GSTEP(&fcT[u * 128 + iq * 4], &sh_old[half][u - 64][bq]);
    }
    COMBINE;
    if (ul == 0) {
        const float* fcb = half ? fc2_b : fc1_b;
        #pragma unroll
        for (int c = 0; c < 4; ++c) {
            const float bias = fcb[iq * 4 + c];
            *(float4*)&sh_e[half][iq * 4 + c][bq] =
                make_float4(fsig(a[c][0] + bias), fsig(a[c][1] + bias),
                            fsig(a[c][2] + bias), fsig(a[c][3] + bias));
        }
    }
    __syncthreads();

    // ---- stage 3: ses[mat][b][j] = exp2( -log2e * dot128(e, Wa[j]) ) ----
    CLR;
    {
        const float* WT = half ? W2aT : W1aT;
        #pragma unroll 4
        for (int u = ul; u < 128; u += 4)
            GSTEP(&WT[u * 128 + iq * 4], &sh_e[half][u][bq]);
    }
    COMBINE;
    if (ul == 0) {
        #pragma unroll
        for (int c = 0; c < 4; ++c) {
            #pragma unroll
            for (int b = 0; b < 4; ++b)
                ses[half][bq + b][iq * 4 + c] = fexp2(-LOG2E * a[c][b]);
        }
    }
#undef CLR
#undef FMAC
#undef GSTEP
#undef COMBINE
    __syncthreads();

    // ---- main loop: k = t&127 on lanes, jq = t>>7 (j-quarter) ----
    // Each thread: 8 b x 32 j x 1 k; E read exactly once per block.
    const int k  = t & 127;
    const int jq = t >> 7;                // 0..3

    const float4* E1v = (const float4*)E1i + k;
    const float4* E2v = (const float4*)E2i + k;

    float acc[8];
    #pragma unroll
    for (int b = 0; b < 8; ++b) acc[b] = 0.f;

#define COMP(acc_, s1c, s2c, e1c, e2c, w3c) { \
        const float uu = (s1c) * (e1c); \
        const float vv = (s2c) * (e2c); \
        const float dd = frcp((1.f + uu) * (1.f + vv)); \
        acc_ = fmaf((vv - uu) * dd, (w3c), acc_); }

    #pragma unroll 2
    for (int i = 0; i < 8; ++i) {
        const int j4 = jq * 8 + i;
        const int j  = j4 * 4;
        const float4 e1 = E1v[j4 * 128];
        const float4 e2 = E2v[j4 * 128];
        const float4 w3 = *(const float4*)&W3[j];
        #pragma unroll
        for (int b = 0; b < 8; ++b) {
            const float4 p1 = *(const float4*)&ses[0][b][j];
            const float4 p2 = *(const float4*)&ses[1][b][j];
            COMP(acc[b], p1.x, p2.x, e1.x, e2.x, w3.x);
            COMP(acc[b], p1.y, p2.y, e1.y, e2.y, w3.y);
            COMP(acc[b], p1.z, p2.z, e1.z, e2.z, w3.z);
            COMP(acc[b], p1.w, p2.w, e1.w, e2.w, w3.w);
        }
    }
#undef COMP

    // ---- store j-quarter partials (lanes on k -> conflict-free) ----
    #pragma unroll
    for (int b = 0; b < 8; ++b) red[jq][b][k] = acc[b];
    __syncthreads();

    // ---- combine quarters + outer sigmoid + kn-weighted k-mean ----
    {
        const float bb3 = b3[0];
        float co[2], ck[2];
        #pragma unroll
        for (int h = 0; h < 2; ++h) {
            const int item = t + h * 512;      // 0..1023 = b*128 + k
            const int b    = item >> 7;
            const int kk   = item & 127;
            const float s  = red[0][b][kk] + red[1][b][kk]
                           + red[2][b][kk] + red[3][b][kk];
            const float o  = fsig(s + bb3);
            const float kv = kn[(b0 + b) * 128 + kk];
            co[h] = o * kv;
            ck[h] = kv;
        }
        #pragma unroll
        for (int off = 1; off < 64; off <<= 1) {
            co[0] += __shfl_xor(co[0], off);
            ck[0] += __shfl_xor(ck[0], off);
            co[1] += __shfl_xor(co[1], off);
            ck[1] += __shfl_xor(ck[1], off);
        }
        // wave w covers b = w>>1 (h=0) and b+4 (h=1), k-half = w&1
        if ((t & 63) == 0) {
            const int b_  = w >> 1;
            const int kh  = w & 1;
            red2_o[b_][kh]     = co[0];
            red2_k[b_][kh]     = ck[0];
            red2_o[b_ + 4][kh] = co[1];
            red2_k[b_ + 4][kh] = ck[1];
        }
    }
    __syncthreads();
    if (t < 8) {
        const float so = red2_o[t][0] + red2_o[t][1];
        const float sk = red2_k[t][0] + red2_k[t][1];
        out[b0 + t] = so / sk;
    }
}

// ---------------------------------------------------------------------------
extern "C" void kernel_launch(void* const* d_in, const int* in_sizes, int n_in,
                              void* d_out, int out_size, void* d_ws, size_t ws_size,
                              hipStream_t stream)
{
    const int*   stu_id      = (const int*)  d_in[0];
    const int*   exer_id     = (const int*)  d_in[1];
    const float* kn_emb      = (const float*)d_in[2];
    const float* student_emb = (const float*)d_in[3];
    const float* prompt_stu  = (const float*)d_in[4];
    const float* kle         = (const float*)d_in[5];
    const float* k_diff      = (const float*)d_in[6];
    const float* s_exer      = (const float*)d_in[7];
    const float* W1          = (const float*)d_in[8];
    const float* W2          = (const float*)d_in[9];
    const float* W3          = (const float*)d_in[10];
    const float* b3          = (const float*)d_in[11];
    const float* fc1_W       = (const float*)d_in[12];
    const float* fc1_b       = (const float*)d_in[13];
    const float* fc2_W       = (const float*)d_in[14];
    const float* fc2_b       = (const float*)d_in[15];
    float* out = (float*)d_out;

    float* ws   = (float*)d_ws;
    float* kleT = ws;                        // 64*128   = 8192
    float* fc1T = kleT + 8192;               // 192*128  = 24576
    float* fc2T = fc1T + 24576;
    float* W1aT = fc2T + 24576;              // 128*128  = 16384
    float* W2aT = W1aT + 16384;
    float* E1i  = W2aT + 16384;              // 128*128  = 16384
    float* E2i  = E1i  + 16384;

    k_pre  <<<960, 128, 0, stream>>>(kle, W1, W2, fc1_W, fc2_W,
                                     kleT, fc1T, fc2T, W1aT, W2aT, E1i, E2i);
    k_fused<<<BATCH / 8, 512, 0, stream>>>(stu_id, exer_id, student_emb, prompt_stu,
                                           k_diff, s_exer, kleT, fc1T, fc2T,
                                           W1aT, W2aT, fc1_b, fc2_b,
                                           E1i, E2i, W3, b3, kn_emb, out);
}